// Round 9
// baseline (48.935 us; speedup 1.0000x reference)
//
#include <hip/hip_runtime.h>
#include <cfloat>

#define KK 5
#define BB 8
#define NN 200
#define DD 512

// ---------------------------------------------------------------------------
// Kernel A: per-batch distances + top-5 (smallest) + z_score + minmap init.
// 512 threads/block, one block per batch. Each ROW's squared distance is
// split across 2 threads (64 float4 loads each instead of 128 -> half the
// serial latency chain), combined in LDS. Then wave-0 packed-u64 butterfly
// argmin (proven in round 7): value<<32|index, min == (value, lowest idx on
// ties) == jax.lax.top_k selection set. Also re-inits minmaps to +INF (ws is
// NOT re-poisoned between replays; atomicMin needs a known start).
// ---------------------------------------------------------------------------
__device__ __forceinline__ unsigned long long umin64(unsigned long long a,
                                                     unsigned long long b)
{ return b < a ? b : a; }

__global__ __launch_bounds__(512) void topk_kernel(
    const float* __restrict__ z, const float* __restrict__ zlib,
    float* __restrict__ zscore, int* __restrict__ idx_out,
    unsigned* __restrict__ minmaps, int mm_total)
{
    int b   = blockIdx.x;   // 0..7
    int tid = threadIdx.x;  // 0..511

    // init all min-maps to +inf (0x7F800000): 8*512 threads cover 32928 words
    for (int i = b * 512 + tid; i < mm_total; i += BB * 512)
        minmaps[i] = 0x7F800000u;

    __shared__ float4 zs4[DD / 4];     // 128 float4
    __shared__ float  part[256][2];    // per-(row,half) partial sums
    __shared__ float  dist[256];
    if (tid < DD / 4)
        zs4[tid] = ((const float4*)(z + b * DD))[tid];
    __syncthreads();

    {
        int n = tid >> 1;          // row 0..255
        int h = tid & 1;           // half
        float acc = 0.f;
        if (n < NN) {
            const float4* lrow = (const float4*)(zlib + (size_t)n * DD) + h * 64;
            const float4* zrow = zs4 + h * 64;
#pragma unroll 8
            for (int c = 0; c < 64; ++c) {
                float4 a = zrow[c];
                float4 l = lrow[c];
                float dx = a.x - l.x, dy = a.y - l.y;
                float dz = a.z - l.z, dw = a.w - l.w;
                acc = fmaf(dx, dx, fmaf(dy, dy, fmaf(dz, dz, fmaf(dw, dw, acc))));
            }
        }
        part[n][h] = acc;
    }
    __syncthreads();
    if (tid < 256)
        dist[tid] = (tid < NN) ? sqrtf(fmaxf(part[tid][0] + part[tid][1], 0.f))
                               : FLT_MAX;
    __syncthreads();

    // wave 0: packed u64 top-5
    if (tid < 64) {
        unsigned long long pk[4];
#pragma unroll
        for (int j = 0; j < 4; ++j) {
            int n = tid + 64 * j;
            pk[j] = ((unsigned long long)__float_as_uint(dist[n]) << 32)
                  | (unsigned)n;
        }
        float sum = 0.f;
        for (int r = 0; r < KK; ++r) {
            unsigned long long p = umin64(umin64(pk[0], pk[1]),
                                          umin64(pk[2], pk[3]));
#pragma unroll
            for (int m = 32; m; m >>= 1)
                p = umin64(p, __shfl_xor(p, m));
            unsigned widx = (unsigned)(p & 0xFFFFFFFFu);
            sum += __uint_as_float((unsigned)(p >> 32));
            if (tid == 0) idx_out[b * KK + r] = (int)widx;
#pragma unroll
            for (int j = 0; j < 4; ++j)
                if ((unsigned)(pk[j] & 0xFFFFFFFFu) == widx)
                    pk[j] = 0xFFFFFFFFFFFFFFFFull;
        }
        if (tid == 0) zscore[b] = sum * (1.f / KK);
    }
}

// ---------------------------------------------------------------------------
// Kernel B: thread per (k,b,2 pixels); sum over channels of squared diff
// (float2 loads halve issued load instructions at full coalescing),
// atomicMin into per-scale min-map (float-as-uint order-preserving for
// non-negative). 323 blocks / 1292 waves -> all CUs engaged, ~10 MB
// loads-in-flight capacity >> 1.6 MB Little's-law requirement.
// ---------------------------------------------------------------------------
template <int C, int HW>
__device__ __forceinline__ void smap_body2(
    const float* __restrict__ fmap, const float* __restrict__ lib,
    const int* __restrict__ idx, unsigned* __restrict__ mm, int gid)
{
    constexpr int HW2 = HW / 2;
    if (gid >= KK * BB * HW2) return;
    int p2 = gid % HW2;
    int r  = gid / HW2;
    int b  = r % BB;
    int k  = r / BB;
    int id = idx[b * KK + k];

    const float2* f = (const float2*)(fmap + (size_t)b  * C * HW) + p2;
    const float2* l = (const float2*)(lib  + (size_t)id * C * HW) + p2;

    float ax = 0.f, ay = 0.f;
#pragma unroll 16
    for (int c = 0; c < C; ++c) {
        float2 lv = l[(size_t)c * HW2];
        float2 fv = f[(size_t)c * HW2];
        float dx = lv.x - fv.x, dy = lv.y - fv.y;
        ax = fmaf(dx, dx, ax);
        ay = fmaf(dy, dy, ay);
    }
    unsigned* m = mm + b * HW + 2 * p2;
    atomicMin(m + 0, __float_as_uint(ax));
    atomicMin(m + 1, __float_as_uint(ay));
}

__global__ __launch_bounds__(256) void smap_kernel(
    const float* __restrict__ fmap0, const float* __restrict__ fmap1,
    const float* __restrict__ fmap2,
    const float* __restrict__ lib0, const float* __restrict__ lib1,
    const float* __restrict__ lib2,
    const int* __restrict__ idx,
    unsigned* __restrict__ mm0, unsigned* __restrict__ mm1,
    unsigned* __restrict__ mm2,
    int nb0, int nb1)
{
    int blk = blockIdx.x;
    if (blk < nb0) {
        smap_body2<64, 3136>(fmap0, lib0, idx, mm0, blk * 256 + threadIdx.x);
    } else if (blk < nb0 + nb1) {
        smap_body2<128, 784>(fmap1, lib1, idx, mm1, (blk - nb0) * 256 + threadIdx.x);
    } else {
        smap_body2<256, 196>(fmap2, lib2, idx, mm2, (blk - nb0 - nb1) * 256 + threadIdx.x);
    }
}

// ---------------------------------------------------------------------------
// Kernel C: bilinear upsample (half-pixel, edge-clamped == jax.image.resize
// "bilinear" for pure upsampling) of the 3 min-maps (132 KB, L2-resident),
// summed. 12 taps per output pixel.
// ---------------------------------------------------------------------------
__device__ __forceinline__ float bil(const unsigned* __restrict__ m, int S,
                                     int oy, int ox)
{
    float scale = (float)S * (1.f / 224.f);
    float sy = fminf(fmaxf((oy + 0.5f) * scale - 0.5f, 0.f), (float)(S - 1));
    float sx = fminf(fmaxf((ox + 0.5f) * scale - 0.5f, 0.f), (float)(S - 1));
    int y0 = (int)sy, x0 = (int)sx;
    float ty = sy - y0, tx = sx - x0;
    int y1 = min(y0 + 1, S - 1), x1 = min(x0 + 1, S - 1);
    float v00 = __uint_as_float(m[y0 * S + x0]);
    float v01 = __uint_as_float(m[y0 * S + x1]);
    float v10 = __uint_as_float(m[y1 * S + x0]);
    float v11 = __uint_as_float(m[y1 * S + x1]);
    float top = v00 + tx * (v01 - v00);
    float bot = v10 + tx * (v11 - v10);
    return top + ty * (bot - top);
}

__global__ __launch_bounds__(256) void upsample_kernel(
    const unsigned* __restrict__ mm0, const unsigned* __restrict__ mm1,
    const unsigned* __restrict__ mm2, float* __restrict__ out)
{
    int gid = blockIdx.x * 256 + threadIdx.x;   // over 8*224*224
    if (gid >= BB * 224 * 224) return;
    int ox = gid % 224;
    int r  = gid / 224;
    int oy = r % 224;
    int b  = r / 224;

    float v = bil(mm0 + b * 3136, 56, oy, ox)
            + bil(mm1 + b * 784,  28, oy, ox)
            + bil(mm2 + b * 196,  14, oy, ox);
    out[BB + gid] = v;   // first 8 floats are z_score
}

// ---------------------------------------------------------------------------
extern "C" void kernel_launch(void* const* d_in, const int* in_sizes, int n_in,
                              void* d_out, int out_size, void* d_ws, size_t ws_size,
                              hipStream_t stream)
{
    const float* z     = (const float*)d_in[0];
    const float* zlib  = (const float*)d_in[1];
    const float* fmap0 = (const float*)d_in[2];
    const float* fmap1 = (const float*)d_in[3];
    const float* fmap2 = (const float*)d_in[4];
    const float* lib0  = (const float*)d_in[5];
    const float* lib1  = (const float*)d_in[6];
    const float* lib2  = (const float*)d_in[7];
    float* out = (float*)d_out;

    char* ws = (char*)d_ws;
    int*      idx = (int*)ws;                      // 40 ints
    unsigned* mm0 = (unsigned*)(ws + 256);         // 8*3136
    unsigned* mm1 = mm0 + BB * 3136;               // 8*784
    unsigned* mm2 = mm1 + BB * 784;                // 8*196
    const int mm_total = BB * (3136 + 784 + 196);  // 32928

    topk_kernel<<<BB, 512, 0, stream>>>(z, zlib, out, idx, mm0, mm_total);

    // float2 blocks: scale0: 5*8*1568/256 = 245; scale1: ceil(15680/256)=62;
    // scale2: ceil(3920/256)=16  => 323 blocks
    smap_kernel<<<323, 256, 0, stream>>>(fmap0, fmap1, fmap2,
                                         lib0, lib1, lib2,
                                         idx, mm0, mm1, mm2, 245, 62);

    upsample_kernel<<<1568, 256, 0, stream>>>(mm0, mm1, mm2, out);
}